// Round 6
// baseline (509.586 us; speedup 1.0000x reference)
//
#include <hip/hip_runtime.h>
#include <hip/hip_bf16.h>

#define HIDDEN 1024
#define INTER  2048
#define NEXP   8
#define BM 128
#define BN 128
#define BK 32

typedef __bf16 bf16_t;
typedef __bf16 bf16x4 __attribute__((ext_vector_type(4)));
typedef __bf16 bf16x8 __attribute__((ext_vector_type(8)));
typedef float  f32x4  __attribute__((ext_vector_type(4)));

__device__ __forceinline__ void async_cp16(const bf16_t* g, bf16_t* l) {
    __builtin_amdgcn_global_load_lds(
        (const __attribute__((address_space(1))) unsigned int*)g,
        (__attribute__((address_space(3))) unsigned int*)l, 16, 0, 0);
}

// bank-conflict-free chunk swizzle (verified 0 conflicts rounds 0/3/4)
__device__ __forceinline__ int swz(int r) { return (r >> 1) & 3; }

// hdr layout (ints):
//  [0..7]=cnt2  [8..15]=cnt1  [24..31]=seg_base  [32..39]=seg_cap
//  [48..55]=hist2 (atomic)  [56..63]=hist1 (atomic)  [64..71]=cur (atomic)

// ---------------- prep: transpose-convert W1/W2 (blocks 0..8191) --------------
//                  + router (blocks 8192..10239), co-resident & overlapped ----
#define NTBLK 8192
__global__ __launch_bounds__(256) void prep_kernel(
    const float* __restrict__ x, const float* __restrict__ wr,
    const float* __restrict__ w1, const float* __restrict__ w2,
    bf16_t* __restrict__ w1t, bf16_t* __restrict__ w2t,
    int* __restrict__ top_e, float* __restrict__ top_w,
    float* __restrict__ psums, bf16_t* __restrict__ xbf, int* __restrict__ hdr)
{
    __shared__ __align__(16) float smem[NEXP * HIDDEN + 32];   // 32.1 KB union
    int tid = threadIdx.x;
    int bid = blockIdx.x;

    if (bid == 0 && tid < 32) hdr[48 + tid] = 0;   // hist2/hist1/cur

    if (bid < NTBLK) {
        // ---- transpose path: [R][C]f32 -> [C][R]bf16, 64x64 tiles ----
        int z = bid >> 9, l = bid & 511;
        const float* src; bf16_t* dst; int R, C, e, bx, by;
        if (z < 8) {
            src = w1; dst = w1t; R = HIDDEN; C = INTER;
            e = z; bx = l & 31; by = l >> 5;
        } else {
            src = w2; dst = w2t; R = INTER; C = HIDDEN;
            e = z - 8; bx = l & 15; by = l >> 4;
        }
        float (*tile)[65] = (float(*)[65])smem;
        int r0 = by * 64, c0 = bx * 64;

        int r = tid >> 4;              // 0..15
        int cq = (tid & 15) * 4;       // 0..60
        const float* s = src + ((size_t)e * R + r0 + r) * C + c0 + cq;
#pragma unroll
        for (int j = 0; j < 4; j++) {
            float4 v = *(const float4*)(s + (size_t)j * 16 * C);
            tile[r + j * 16][cq + 0] = v.x;
            tile[r + j * 16][cq + 1] = v.y;
            tile[r + j * 16][cq + 2] = v.z;
            tile[r + j * 16][cq + 3] = v.w;
        }
        __syncthreads();

        int c = tid >> 2;              // 0..63
        int rq = (tid & 3) * 16;       // 0,16,32,48
        bf16_t* d = dst + ((size_t)e * C + c0 + c) * R + r0 + rq;
        bf16x8 o0, o1;
#pragma unroll
        for (int j = 0; j < 8; j++) o0[j] = (bf16_t)tile[rq + j][c];
#pragma unroll
        for (int j = 0; j < 8; j++) o1[j] = (bf16_t)tile[rq + 8 + j][c];
        *(bf16x8*)(d + 0) = o0;
        *(bf16x8*)(d + 8) = o1;
        return;
    }

    // ---- router path: fp64 logits, per-block psums, NO atomics ----
    int rb = bid - NTBLK;
    float* wl = smem;                       // [e][h], 32 KB
    float (*psl)[NEXP] = (float(*)[NEXP])(smem + NEXP * HIDDEN);

    for (int i = tid; i < HIDDEN * NEXP / 4; i += 256) {
        float4 v = *(const float4*)(wr + i * 4);
        int m = i * 4, h = m >> 3, e = m & 7;
        wl[(e + 0) * HIDDEN + h] = v.x;
        wl[(e + 1) * HIDDEN + h] = v.y;
        wl[(e + 2) * HIDDEN + h] = v.z;
        wl[(e + 3) * HIDDEN + h] = v.w;
    }
    __syncthreads();

    int lane = tid & 63, wave = tid >> 6;
    int tok = rb * 4 + wave;
    const float* xr = x + (size_t)tok * HIDDEN;

    float xv[16];
#pragma unroll
    for (int j = 0; j < 16; j++) xv[j] = xr[lane + 64 * j];

    bf16_t* xbr = xbf + (size_t)tok * HIDDEN;
#pragma unroll
    for (int j = 0; j < 16; j++) xbr[lane + 64 * j] = (bf16_t)xv[j];

    double acc[NEXP];
#pragma unroll
    for (int e = 0; e < NEXP; e++) acc[e] = 0.0;
#pragma unroll
    for (int j = 0; j < 16; j++) {
        int h = lane + 64 * j;
#pragma unroll
        for (int e = 0; e < NEXP; e++)
            acc[e] += (double)xv[j] * (double)wl[e * HIDDEN + h];
    }
#pragma unroll
    for (int e = 0; e < NEXP; e++) {
        double v = acc[e];
#pragma unroll
        for (int off = 32; off > 0; off >>= 1) v += __shfl_down(v, off);
        acc[e] = v;
    }
    if (lane == 0) {
        int e0 = 0;
#pragma unroll
        for (int e = 1; e < NEXP; e++) if (acc[e] > acc[e0]) e0 = e;
        int e1 = (e0 == 0) ? 1 : 0;
#pragma unroll
        for (int e = 0; e < NEXP; e++) if (e != e0 && acc[e] > acc[e1]) e1 = e;
        double w0 = 1.0 / (1.0 + exp(acc[e1] - acc[e0]));
        top_e[tok * 2 + 0] = e0;
        top_e[tok * 2 + 1] = e1;
        top_w[tok * 2 + 0] = (float)w0;
        top_w[tok * 2 + 1] = (float)(1.0 - w0);
        float mx = (float)acc[0];
#pragma unroll
        for (int e = 1; e < NEXP; e++) mx = fmaxf(mx, (float)acc[e]);
        float p[NEXP], s = 0.f;
#pragma unroll
        for (int e = 0; e < NEXP; e++) { p[e] = __expf((float)acc[e] - mx); s += p[e]; }
#pragma unroll
        for (int e = 0; e < NEXP; e++) psl[wave][e] = p[e] / s;
    }
    __syncthreads();
    if (tid < NEXP)
        psums[rb * NEXP + tid] =
            psl[0][tid] + psl[1][tid] + psl[2][tid] + psl[3][tid];
}

// ------- Histogram: 32 blocks, LDS-aggregated, 16 atomics per block -----------
__global__ __launch_bounds__(256) void hist_kernel(
    const int* __restrict__ top_e, int* __restrict__ hdr)
{
    __shared__ int wcnt[4][16];
    int tid = threadIdx.x, lane = tid & 63, wave = tid >> 6;
    int t = blockIdx.x * 256 + tid;
    int e0 = top_e[t * 2 + 0];
    int e1 = top_e[t * 2 + 1];
#pragma unroll
    for (int e = 0; e < NEXP; e++) {
        unsigned long long m0 = __ballot(e0 == e);
        unsigned long long m1 = __ballot(e1 == e);
        if (lane == 0) {
            wcnt[wave][e] = __popcll(m0) + __popcll(m1);   // c2
            wcnt[wave][8 + e] = __popcll(m0);              // c1
        }
    }
    __syncthreads();
    if (tid < 16) {
        int s = wcnt[0][tid] + wcnt[1][tid] + wcnt[2][tid] + wcnt[3][tid];
        atomicAdd(&hdr[48 + tid], s);    // [48..55]=c2, [56..63]=c1
    }
}

// ------- tiny single-block: segments + aux + padding fill ---------------------
__global__ __launch_bounds__(256) void setup_kernel(
    int* __restrict__ hdr, const float* __restrict__ psums, int nblk,
    int* __restrict__ row_tok, float* __restrict__ aux_out, int n)
{
    __shared__ int s_sc2[NEXP], s_segb[NEXP], s_cap[NEXP];
    __shared__ float pred[NEXP];
    int tid = threadIdx.x, lane = tid & 63;
    if (tid < NEXP) pred[tid] = 0.f;
    __syncthreads();
    {
        float ps = 0.f;
        int e = tid & 7;
        for (int i = tid >> 3; i < nblk; i += 32) ps += psums[i * NEXP + e];
        ps += __shfl_down(ps, 32);
        ps += __shfl_down(ps, 16);
        ps += __shfl_down(ps, 8);
        if (lane < 8) atomicAdd(&pred[lane], ps);
    }
    __syncthreads();
    if (tid == 0) {
        int off = 0;
        double aux = 0.0;
#pragma unroll
        for (int e = 0; e < NEXP; e++) {
            int c2 = hdr[48 + e], c1 = hdr[56 + e];
            int cap = (c2 + BM - 1) / BM * BM;
            hdr[e] = c2; hdr[8 + e] = c1;
            hdr[24 + e] = off; hdr[32 + e] = cap;
            hdr[64 + e] = off;                 // cur counter init for scatter
            s_sc2[e] = c2; s_segb[e] = off; s_cap[e] = cap;
            aux += ((double)c1 / n) * ((double)pred[e] / n);
            off += cap;
        }
        *aux_out = (float)(aux * NEXP);
    }
    __syncthreads();
#pragma unroll
    for (int e = 0; e < NEXP; e++)
        for (int r = s_sc2[e] + tid; r < s_cap[e]; r += 256)
            row_tok[s_segb[e] + r] = -1;
}

// ------- parallel scatter: wave-aggregated atomic row assignment --------------
__global__ __launch_bounds__(256) void scatter_kernel(
    const int* __restrict__ top_e, int* __restrict__ hdr,
    int* __restrict__ row_tok, int* __restrict__ row_of)
{
    int t = blockIdx.x * 256 + threadIdx.x;
    int lane = threadIdx.x & 63;
    int e0 = top_e[t * 2 + 0];
    int e1 = top_e[t * 2 + 1];
    unsigned long long below = (lane == 63) ? ~0ull >> 1 : (1ull << lane) - 1;
#pragma unroll
    for (int e = 0; e < NEXP; e++) {
        unsigned long long m0 = __ballot(e0 == e);
        unsigned long long m1 = __ballot(e1 == e);
        int c0 = __popcll(m0);
        int c = c0 + __popcll(m1);
        int base = 0;
        if (lane == 0 && c) base = atomicAdd(&hdr[64 + e], c);
        base = __shfl(base, 0);
        if (e0 == e) {
            int r = base + __popcll(m0 & below);
            row_tok[r] = t; row_of[t * 2 + 0] = r;
        }
        if (e1 == e) {
            int r = base + c0 + __popcll(m1 & below);
            row_tok[r] = t; row_of[t * 2 + 1] = r;
        }
    }
}

// ---------------- expert lookup ----------------------------------------------
__device__ __forceinline__ int tile_expert(const int* hdr, int row0)
{
    int e = -1;
#pragma unroll
    for (int i = 0; i < NEXP; i++) {
        int sb = hdr[24 + i];
        if (row0 >= sb && row0 < sb + hdr[32 + i]) e = i;
    }
    if (e >= 0 && row0 - hdr[24 + e] >= hdr[e]) e = -1;
    return e;
}

// ------- GEMM helper macros: 4-deep counted-vmcnt pipeline --------------------
// Protocol per iter i: s_waitcnt vmcnt(8) [tile i's 4 loads done; tiles
// i+1,i+2 stay in flight] -> s_barrier -> STAGE(i+3) -> STEP(i&3).
// sched_barrier(0) pins: s_barrier builtin is NOT a compiler memory fence,
// so without pins LLVM may hoist STAGE above the barrier (cross-wave WAR).

#define G_WAIT(N) do {                                                         \
    asm volatile("s_waitcnt vmcnt(" #N ")" ::: "memory");                      \
    __builtin_amdgcn_sched_barrier(0); } while (0)

#define G_BARRIER() do {                                                       \
    __builtin_amdgcn_sched_barrier(0);                                         \
    __builtin_amdgcn_s_barrier();                                              \
    __builtin_amdgcn_sched_barrier(0); } while (0)

#define G_STAGE(t) do { int ko_ = (t) * BK, bb_ = (t) & 3;                     \
    async_cp16(ag0 + ko_, As[bb_] + tid * 8);                                  \
    async_cp16(ag1 + ko_, As[bb_] + (tid + 256) * 8);                          \
    async_cp16(bg0 + ko_, Bs[bb_] + tid * 8);                                  \
    async_cp16(bg1 + ko_, Bs[bb_] + (tid + 256) * 8); } while (0)

#define G_STEP(b) do {                                                         \
    const bf16_t* Ab_ = As[b]; const bf16_t* Bb_ = Bs[b];                      \
    bf16x8 af_[4], bf_[4];                                                     \
    _Pragma("unroll") for (int ii_ = 0; ii_ < 4; ii_++) {                      \
        af_[ii_] = *(const bf16x8*)(Ab_ + aoff[ii_]);                          \
        bf_[ii_] = *(const bf16x8*)(Bb_ + boff[ii_]);                          \
    }                                                                          \
    _Pragma("unroll") for (int mi_ = 0; mi_ < 4; mi_++)                        \
    _Pragma("unroll") for (int nj_ = 0; nj_ < 4; nj_++)                        \
        acc[mi_][nj_] = __builtin_amdgcn_mfma_f32_16x16x32_bf16(               \
            bf_[nj_], af_[mi_], acc[mi_][nj_], 0, 0, 0); } while (0)

// ---------------- GEMM1: Hbuf = silu(X[rows] @ W1[e]) -------------------------
__global__ __launch_bounds__(256) void gemm1_kernel(
    const bf16_t* __restrict__ xbf, const bf16_t* __restrict__ w1t,
    const int* __restrict__ hdr, const int* __restrict__ row_tok,
    bf16_t* __restrict__ Hbuf)
{
    __shared__ __align__(16) bf16_t As[4][BM * BK];
    __shared__ __align__(16) bf16_t Bs[4][BN * BK];

    int row0 = blockIdx.x * BM;
    int e = tile_expert(hdr, row0);
    if (e < 0) return;
    int n0 = blockIdx.y * BN;
    int tid = threadIdx.x;

    int ar0 = tid >> 2, as0 = tid & 3, ak0 = as0 ^ swz(ar0);
    int ar1 = ar0 + 64, ak1 = as0 ^ swz(ar1);
    int t0 = row_tok[row0 + ar0]; if (t0 < 0) t0 = 0;
    int t1 = row_tok[row0 + ar1]; if (t1 < 0) t1 = 0;
    const bf16_t* ag0 = xbf + (size_t)t0 * HIDDEN + ak0 * 8;
    const bf16_t* ag1 = xbf + (size_t)t1 * HIDDEN + ak1 * 8;
    const bf16_t* wb = w1t + (size_t)e * HIDDEN * INTER;
    const bf16_t* bg0 = wb + (size_t)(n0 + ar0) * HIDDEN + ak0 * 8;
    const bf16_t* bg1 = wb + (size_t)(n0 + ar1) * HIDDEN + ak1 * 8;

    int wave = tid >> 6, lane = tid & 63;
    int wm = (wave >> 1) * 64, wn = (wave & 1) * 64;
    int lrow = lane & 15, q = lane >> 4;

    int aoff[4], boff[4];
#pragma unroll
    for (int i = 0; i < 4; i++) {
        int r = wm + i * 16 + lrow;
        aoff[i] = r * BK + (q ^ swz(r)) * 8;
        int s = wn + i * 16 + lrow;
        boff[i] = s * BK + (q ^ swz(s)) * 8;
    }

    f32x4 acc[4][4] = {};

    const int NK = HIDDEN / BK;     // 32
    G_STAGE(0); G_STAGE(1); G_STAGE(2);

    for (int i = 0; i < NK - 2; ++i) {
        G_WAIT(8);
        G_BARRIER();
        if (i + 3 < NK) G_STAGE(i + 3);
        G_STEP(i & 3);
    }
    G_WAIT(4);
    G_BARRIER();
    G_STEP((NK - 2) & 3);
    G_WAIT(0);
    G_BARRIER();
    G_STEP((NK - 1) & 3);

#pragma unroll
    for (int mi = 0; mi < 4; mi++) {
        size_t rb = (size_t)(row0 + wm + mi * 16 + lrow) * INTER + n0 + wn + q * 4;
#pragma unroll
        for (int nj = 0; nj < 4; nj++) {
            f32x4 v = acc[mi][nj];
            bf16x4 o = {
                (bf16_t)(v.x * __builtin_amdgcn_rcpf(1.f + __expf(-v.x))),
                (bf16_t)(v.y * __builtin_amdgcn_rcpf(1.f + __expf(-v.y))),
                (bf16_t)(v.z * __builtin_amdgcn_rcpf(1.f + __expf(-v.z))),
                (bf16_t)(v.w * __builtin_amdgcn_rcpf(1.f + __expf(-v.w))) };
            *(bf16x4*)(Hbuf + rb + nj * 16) = o;
        }
    }
}

// ---------------- GEMM2: Obuf = Hbuf[rows] @ W2[e] ----------------------------
__global__ __launch_bounds__(256) void gemm2_kernel(
    const bf16_t* __restrict__ Hbuf, const bf16_t* __restrict__ w2t,
    const int* __restrict__ hdr, bf16_t* __restrict__ Obuf)
{
    __shared__ __align__(16) bf16_t As[4][BM * BK];
    __shared__ __align__(16) bf16_t Bs[4][BN * BK];

    int row0 = blockIdx.x * BM;
    int e = tile_expert(hdr, row0);
    if (e < 0) return;
    int n0 = blockIdx.y * BN;
    int tid = threadIdx.x;

    int ar0 = tid >> 2, as0 = tid & 3, ak0 = as0 ^ swz(ar0);
    int ar1 = ar0 + 64, ak1 = as0 ^ swz(ar1);
    const bf16_t* ag0 = Hbuf + (size_t)(row0 + ar0) * INTER + ak0 * 8;
    const bf16_t* ag1 = Hbuf + (size_t)(row0 + ar1) * INTER + ak1 * 8;
    const bf16_t* wb = w2t + (size_t)e * HIDDEN * INTER;
    const bf16_t* bg0 = wb + (size_t)(n0 + ar0) * INTER + ak0 * 8;
    const bf16_t* bg1 = wb + (size_t)(n0 + ar1) * INTER + ak1 * 8;

    int wave = tid >> 6, lane = tid & 63;
    int wm = (wave >> 1) * 64, wn = (wave & 1) * 64;
    int lrow = lane & 15, q = lane >> 4;

    int aoff[4], boff[4];
#pragma unroll
    for (int i = 0; i < 4; i++) {
        int r = wm + i * 16 + lrow;
        aoff[i] = r * BK + (q ^ swz(r)) * 8;
        int s = wn + i * 16 + lrow;
        boff[i] = s * BK + (q ^ swz(s)) * 8;
    }

    f32x4 acc[4][4] = {};

    const int NK = INTER / BK;      // 64
    G_STAGE(0); G_STAGE(1); G_STAGE(2);

    for (int i = 0; i < NK - 2; ++i) {
        G_WAIT(8);
        G_BARRIER();
        if (i + 3 < NK) G_STAGE(i + 3);
        G_STEP(i & 3);
    }
    G_WAIT(4);
    G_BARRIER();
    G_STEP((NK - 2) & 3);
    G_WAIT(0);
    G_BARRIER();
    G_STEP((NK - 1) & 3);

#pragma unroll
    for (int mi = 0; mi < 4; mi++) {
        size_t rb = (size_t)(row0 + wm + mi * 16 + lrow) * HIDDEN + n0 + wn + q * 4;
#pragma unroll
        for (int nj = 0; nj < 4; nj++) {
            f32x4 v = acc[mi][nj];
            bf16x4 o = { (bf16_t)v.x, (bf16_t)v.y, (bf16_t)v.z, (bf16_t)v.w };
            *(bf16x4*)(Obuf + rb + nj * 16) = o;
        }
    }
}

// ---------------- Combine: out[t] = w0*Obuf[r0] + w1*Obuf[r1] -----------------
__global__ __launch_bounds__(256) void combine_kernel(
    const bf16_t* __restrict__ Obuf, const int* __restrict__ row_of,
    const float* __restrict__ top_w, float* __restrict__ out)
{
    int t = blockIdx.x;
    int r0 = row_of[t * 2 + 0], r1 = row_of[t * 2 + 1];
    float w0 = top_w[t * 2 + 0], w1 = top_w[t * 2 + 1];
    int c = threadIdx.x * 4;
    bf16x4 a = *(const bf16x4*)(Obuf + (size_t)r0 * HIDDEN + c);
    bf16x4 b = *(const bf16x4*)(Obuf + (size_t)r1 * HIDDEN + c);
    float4 o;
    o.x = w0 * (float)a.x + w1 * (float)b.x;
    o.y = w0 * (float)a.y + w1 * (float)b.y;
    o.z = w0 * (float)a.z + w1 * (float)b.z;
    o.w = w0 * (float)a.w + w1 * (float)b.w;
    *(float4*)(out + (size_t)t * HIDDEN + c) = o;
}

// ---------------- Launch ------------------------------------------------------
extern "C" void kernel_launch(void* const* d_in, const int* in_sizes, int n_in,
                              void* d_out, int out_size, void* d_ws, size_t ws_size,
                              hipStream_t stream)
{
    const float* x  = (const float*)d_in[0];
    const float* wr = (const float*)d_in[1];
    const float* w1 = (const float*)d_in[2];
    const float* w2 = (const float*)d_in[3];
    float* out = (float*)d_out;

    int n = in_sizes[0] / HIDDEN;                                  // 8192
    int nblk = n / 4;                                              // 2048
    int rowcap = ((2 * n + NEXP * (BM - 1)) + BM - 1) / BM * BM;   // 17408

    char* ws = (char*)d_ws;
    int* hdr = (int*)ws;
    size_t off = 512;
    int* row_tok = (int*)(ws + off); off += (size_t)rowcap * 4;
    int* row_of  = (int*)(ws + off); off += (size_t)n * 2 * 4;
    int* top_e   = (int*)(ws + off); off += (size_t)n * 2 * 4;
    float* top_w = (float*)(ws + off); off += (size_t)n * 2 * 4;
    float* psums = (float*)(ws + off); off += (size_t)nblk * NEXP * 4;
    off = (off + 255) & ~(size_t)255;
    size_t xbf_off = off;
    bf16_t* xbf = (bf16_t*)(ws + off);  off += (size_t)n * HIDDEN * 2;
    bf16_t* w1t = (bf16_t*)(ws + off);  off += (size_t)NEXP * HIDDEN * INTER * 2;
    bf16_t* w2t = (bf16_t*)(ws + off);  off += (size_t)NEXP * HIDDEN * INTER * 2;
    bf16_t* Hbuf = (bf16_t*)(ws + off); off += (size_t)rowcap * INTER * 2;
    bf16_t* Obuf = (bf16_t*)(ws + xbf_off);   // aliases xbf+w1t (dead after gemm1)

    prep_kernel<<<NTBLK + nblk, 256, 0, stream>>>(
        x, wr, w1, w2, w1t, w2t, top_e, top_w, psums, xbf, hdr);
    hist_kernel<<<n / 256, 256, 0, stream>>>(top_e, hdr);
    setup_kernel<<<1, 256, 0, stream>>>(hdr, psums, nblk, row_tok,
                                        out + (out_size - 1), n);
    scatter_kernel<<<n / 256, 256, 0, stream>>>(top_e, hdr, row_tok, row_of);

    dim3 g1(rowcap / BM, INTER / BN);
    gemm1_kernel<<<g1, 256, 0, stream>>>(xbf, w1t, hdr, row_tok, Hbuf);
    dim3 g2(rowcap / BM, HIDDEN / BN);
    gemm2_kernel<<<g2, 256, 0, stream>>>(Hbuf, w2t, hdr, Obuf);
    combine_kernel<<<n, 256, 0, stream>>>(Obuf, row_of, top_w, out);
}

// Round 7
// 452.318 us; speedup vs baseline: 1.1266x; 1.1266x over previous
//
#include <hip/hip_runtime.h>
#include <hip/hip_bf16.h>

#define HIDDEN 1024
#define INTER  2048
#define NEXP   8
#define BM 128
#define BN 128
#define BK 32

typedef __bf16 bf16_t;
typedef __bf16 bf16x4 __attribute__((ext_vector_type(4)));
typedef __bf16 bf16x8 __attribute__((ext_vector_type(8)));
typedef float  f32x4  __attribute__((ext_vector_type(4)));

__device__ __forceinline__ void async_cp16(const bf16_t* g, bf16_t* l) {
    __builtin_amdgcn_global_load_lds(
        (const __attribute__((address_space(1))) unsigned int*)g,
        (__attribute__((address_space(3))) unsigned int*)l, 16, 0, 0);
}

// bank-conflict-free chunk swizzle (verified 0 conflicts rounds 0/3/4)
__device__ __forceinline__ int swz(int r) { return (r >> 1) & 3; }

// hdr layout (ints):
//  [0..7]=cnt2  [8..15]=cnt1  [24..31]=seg_base  [32..39]=seg_cap
//  [48..55]=hist2 (atomic)  [56..63]=hist1 (atomic)  [64..71]=cur (atomic)

// ---------------- prep: transpose-convert W1/W2 (blocks 0..8191) --------------
//                  + router (blocks 8192..10239), co-resident & overlapped ----
#define NTBLK 8192
__global__ __launch_bounds__(256) void prep_kernel(
    const float* __restrict__ x, const float* __restrict__ wr,
    const float* __restrict__ w1, const float* __restrict__ w2,
    bf16_t* __restrict__ w1t, bf16_t* __restrict__ w2t,
    int* __restrict__ top_e, float* __restrict__ top_w,
    float* __restrict__ psums, bf16_t* __restrict__ xbf, int* __restrict__ hdr)
{
    __shared__ __align__(16) float smem[NEXP * HIDDEN + 32];   // 32.1 KB union
    int tid = threadIdx.x;
    int bid = blockIdx.x;

    if (bid == 0 && tid < 32) hdr[48 + tid] = 0;   // hist2/hist1/cur

    if (bid < NTBLK) {
        // ---- transpose path: [R][C]f32 -> [C][R]bf16, 64x64 tiles ----
        int z = bid >> 9, l = bid & 511;
        const float* src; bf16_t* dst; int R, C, e, bx, by;
        if (z < 8) {
            src = w1; dst = w1t; R = HIDDEN; C = INTER;
            e = z; bx = l & 31; by = l >> 5;
        } else {
            src = w2; dst = w2t; R = INTER; C = HIDDEN;
            e = z - 8; bx = l & 15; by = l >> 4;
        }
        float (*tile)[65] = (float(*)[65])smem;
        int r0 = by * 64, c0 = bx * 64;

        int r = tid >> 4;              // 0..15
        int cq = (tid & 15) * 4;       // 0..60
        const float* s = src + ((size_t)e * R + r0 + r) * C + c0 + cq;
#pragma unroll
        for (int j = 0; j < 4; j++) {
            float4 v = *(const float4*)(s + (size_t)j * 16 * C);
            tile[r + j * 16][cq + 0] = v.x;
            tile[r + j * 16][cq + 1] = v.y;
            tile[r + j * 16][cq + 2] = v.z;
            tile[r + j * 16][cq + 3] = v.w;
        }
        __syncthreads();

        int c = tid >> 2;              // 0..63
        int rq = (tid & 3) * 16;       // 0,16,32,48
        bf16_t* d = dst + ((size_t)e * C + c0 + c) * R + r0 + rq;
        bf16x8 o0, o1;
#pragma unroll
        for (int j = 0; j < 8; j++) o0[j] = (bf16_t)tile[rq + j][c];
#pragma unroll
        for (int j = 0; j < 8; j++) o1[j] = (bf16_t)tile[rq + 8 + j][c];
        *(bf16x8*)(d + 0) = o0;
        *(bf16x8*)(d + 8) = o1;
        return;
    }

    // ---- router path: fp64 logits, per-block psums, NO atomics ----
    int rb = bid - NTBLK;
    float* wl = smem;                       // [e][h], 32 KB
    float (*psl)[NEXP] = (float(*)[NEXP])(smem + NEXP * HIDDEN);

    for (int i = tid; i < HIDDEN * NEXP / 4; i += 256) {
        float4 v = *(const float4*)(wr + i * 4);
        int m = i * 4, h = m >> 3, e = m & 7;
        wl[(e + 0) * HIDDEN + h] = v.x;
        wl[(e + 1) * HIDDEN + h] = v.y;
        wl[(e + 2) * HIDDEN + h] = v.z;
        wl[(e + 3) * HIDDEN + h] = v.w;
    }
    __syncthreads();

    int lane = tid & 63, wave = tid >> 6;
    int tok = rb * 4 + wave;
    const float* xr = x + (size_t)tok * HIDDEN;

    float xv[16];
#pragma unroll
    for (int j = 0; j < 16; j++) xv[j] = xr[lane + 64 * j];

    bf16_t* xbr = xbf + (size_t)tok * HIDDEN;
#pragma unroll
    for (int j = 0; j < 16; j++) xbr[lane + 64 * j] = (bf16_t)xv[j];

    double acc[NEXP];
#pragma unroll
    for (int e = 0; e < NEXP; e++) acc[e] = 0.0;
#pragma unroll
    for (int j = 0; j < 16; j++) {
        int h = lane + 64 * j;
#pragma unroll
        for (int e = 0; e < NEXP; e++)
            acc[e] += (double)xv[j] * (double)wl[e * HIDDEN + h];
    }
#pragma unroll
    for (int e = 0; e < NEXP; e++) {
        double v = acc[e];
#pragma unroll
        for (int off = 32; off > 0; off >>= 1) v += __shfl_down(v, off);
        acc[e] = v;
    }
    if (lane == 0) {
        int e0 = 0;
#pragma unroll
        for (int e = 1; e < NEXP; e++) if (acc[e] > acc[e0]) e0 = e;
        int e1 = (e0 == 0) ? 1 : 0;
#pragma unroll
        for (int e = 0; e < NEXP; e++) if (e != e0 && acc[e] > acc[e1]) e1 = e;
        double w0 = 1.0 / (1.0 + exp(acc[e1] - acc[e0]));
        top_e[tok * 2 + 0] = e0;
        top_e[tok * 2 + 1] = e1;
        top_w[tok * 2 + 0] = (float)w0;
        top_w[tok * 2 + 1] = (float)(1.0 - w0);
        float mx = (float)acc[0];
#pragma unroll
        for (int e = 1; e < NEXP; e++) mx = fmaxf(mx, (float)acc[e]);
        float p[NEXP], s = 0.f;
#pragma unroll
        for (int e = 0; e < NEXP; e++) { p[e] = __expf((float)acc[e] - mx); s += p[e]; }
#pragma unroll
        for (int e = 0; e < NEXP; e++) psl[wave][e] = p[e] / s;
    }
    __syncthreads();
    if (tid < NEXP)
        psums[rb * NEXP + tid] =
            psl[0][tid] + psl[1][tid] + psl[2][tid] + psl[3][tid];
}

// ------- Histogram: 32 blocks, LDS-aggregated, 16 atomics per block -----------
__global__ __launch_bounds__(256) void hist_kernel(
    const int* __restrict__ top_e, int* __restrict__ hdr)
{
    __shared__ int wcnt[4][16];
    int tid = threadIdx.x, lane = tid & 63, wave = tid >> 6;
    int t = blockIdx.x * 256 + tid;
    int e0 = top_e[t * 2 + 0];
    int e1 = top_e[t * 2 + 1];
#pragma unroll
    for (int e = 0; e < NEXP; e++) {
        unsigned long long m0 = __ballot(e0 == e);
        unsigned long long m1 = __ballot(e1 == e);
        if (lane == 0) {
            wcnt[wave][e] = __popcll(m0) + __popcll(m1);   // c2
            wcnt[wave][8 + e] = __popcll(m0);              // c1
        }
    }
    __syncthreads();
    if (tid < 16) {
        int s = wcnt[0][tid] + wcnt[1][tid] + wcnt[2][tid] + wcnt[3][tid];
        atomicAdd(&hdr[48 + tid], s);    // [48..55]=c2, [56..63]=c1
    }
}

// ------- tiny single-block: segments + aux + padding fill ---------------------
__global__ __launch_bounds__(256) void setup_kernel(
    int* __restrict__ hdr, const float* __restrict__ psums, int nblk,
    int* __restrict__ row_tok, float* __restrict__ aux_out, int n)
{
    __shared__ int s_sc2[NEXP], s_segb[NEXP], s_cap[NEXP];
    __shared__ float pred[NEXP];
    int tid = threadIdx.x, lane = tid & 63;
    if (tid < NEXP) pred[tid] = 0.f;
    __syncthreads();
    {
        float ps = 0.f;
        int e = tid & 7;
        for (int i = tid >> 3; i < nblk; i += 32) ps += psums[i * NEXP + e];
        ps += __shfl_down(ps, 32);
        ps += __shfl_down(ps, 16);
        ps += __shfl_down(ps, 8);
        if (lane < 8) atomicAdd(&pred[lane], ps);
    }
    __syncthreads();
    if (tid == 0) {
        int off = 0;
        double aux = 0.0;
#pragma unroll
        for (int e = 0; e < NEXP; e++) {
            int c2 = hdr[48 + e], c1 = hdr[56 + e];
            int cap = (c2 + BM - 1) / BM * BM;
            hdr[e] = c2; hdr[8 + e] = c1;
            hdr[24 + e] = off; hdr[32 + e] = cap;
            hdr[64 + e] = off;                 // cur counter init for scatter
            s_sc2[e] = c2; s_segb[e] = off; s_cap[e] = cap;
            aux += ((double)c1 / n) * ((double)pred[e] / n);
            off += cap;
        }
        *aux_out = (float)(aux * NEXP);
    }
    __syncthreads();
#pragma unroll
    for (int e = 0; e < NEXP; e++)
        for (int r = s_sc2[e] + tid; r < s_cap[e]; r += 256)
            row_tok[s_segb[e] + r] = -1;
}

// ------- parallel scatter: wave-aggregated atomic row assignment --------------
__global__ __launch_bounds__(256) void scatter_kernel(
    const int* __restrict__ top_e, int* __restrict__ hdr,
    int* __restrict__ row_tok, int* __restrict__ row_of)
{
    int t = blockIdx.x * 256 + threadIdx.x;
    int lane = threadIdx.x & 63;
    int e0 = top_e[t * 2 + 0];
    int e1 = top_e[t * 2 + 1];
    unsigned long long below = (lane == 63) ? ~0ull >> 1 : (1ull << lane) - 1;
#pragma unroll
    for (int e = 0; e < NEXP; e++) {
        unsigned long long m0 = __ballot(e0 == e);
        unsigned long long m1 = __ballot(e1 == e);
        int c0 = __popcll(m0);
        int c = c0 + __popcll(m1);
        int base = 0;
        if (lane == 0 && c) base = atomicAdd(&hdr[64 + e], c);
        base = __shfl(base, 0);
        if (e0 == e) {
            int r = base + __popcll(m0 & below);
            row_tok[r] = t; row_of[t * 2 + 0] = r;
        }
        if (e1 == e) {
            int r = base + c0 + __popcll(m1 & below);
            row_tok[r] = t; row_of[t * 2 + 1] = r;
        }
    }
}

// ---------------- expert lookup ----------------------------------------------
__device__ __forceinline__ int tile_expert(const int* hdr, int row0)
{
    int e = -1;
#pragma unroll
    for (int i = 0; i < NEXP; i++) {
        int sb = hdr[24 + i];
        if (row0 >= sb && row0 < sb + hdr[32 + i]) e = i;
    }
    if (e >= 0 && row0 - hdr[24 + e] >= hdr[e]) e = -1;
    return e;
}

// ---------------- GEMM1: Hbuf = silu(X[rows] @ W1[e]) bf16 MFMA ---------------
// Round-3 exact body: single-buffer BK=32, verified 115.5 us / MfmaUtil 25.9 /
// 0 bank conflicts. Scheduling variants (dbuf, BK=64, 4-deep counted vmcnt)
// all measured neutral-to-worse on this structure (rounds 1/4/6).
__global__ __launch_bounds__(256) void gemm1_kernel(
    const bf16_t* __restrict__ xbf, const bf16_t* __restrict__ w1t,
    const int* __restrict__ hdr, const int* __restrict__ row_tok,
    bf16_t* __restrict__ Hbuf)
{
    __shared__ __align__(16) bf16_t As[BM * BK];
    __shared__ __align__(16) bf16_t Bs[BN * BK];

    int row0 = blockIdx.x * BM;
    int e = tile_expert(hdr, row0);
    if (e < 0) return;
    int n0 = blockIdx.y * BN;
    int tid = threadIdx.x;

    int ar0 = tid >> 2, as0 = tid & 3, ak0 = as0 ^ swz(ar0);
    int ar1 = ar0 + 64, ak1 = as0 ^ swz(ar1);
    int t0 = row_tok[row0 + ar0]; if (t0 < 0) t0 = 0;
    int t1 = row_tok[row0 + ar1]; if (t1 < 0) t1 = 0;
    const bf16_t* ag0 = xbf + (size_t)t0 * HIDDEN + ak0 * 8;
    const bf16_t* ag1 = xbf + (size_t)t1 * HIDDEN + ak1 * 8;
    bf16_t* al0 = As + tid * 8;
    bf16_t* al1 = As + (tid + 256) * 8;

    const bf16_t* wb = w1t + (size_t)e * HIDDEN * INTER;
    const bf16_t* bg0 = wb + (size_t)(n0 + ar0) * HIDDEN + ak0 * 8;
    const bf16_t* bg1 = wb + (size_t)(n0 + ar1) * HIDDEN + ak1 * 8;
    bf16_t* bl0 = Bs + tid * 8;
    bf16_t* bl1 = Bs + (tid + 256) * 8;

    int wave = tid >> 6, lane = tid & 63;
    int wm = (wave >> 1) * 64, wn = (wave & 1) * 64;
    int lrow = lane & 15, q = lane >> 4;

    int aoff[4], boff[4];
#pragma unroll
    for (int i = 0; i < 4; i++) {
        int r = wm + i * 16 + lrow;
        aoff[i] = r * BK + (q ^ swz(r)) * 8;
        int s = wn + i * 16 + lrow;
        boff[i] = s * BK + (q ^ swz(s)) * 8;
    }

    f32x4 acc[4][4] = {};

    for (int k0 = 0; k0 < HIDDEN; k0 += BK) {
        async_cp16(ag0 + k0, al0);
        async_cp16(ag1 + k0, al1);
        async_cp16(bg0 + k0, bl0);
        async_cp16(bg1 + k0, bl1);
        __syncthreads();
        bf16x8 af[4], bfr[4];
#pragma unroll
        for (int i = 0; i < 4; i++) {
            af[i]  = *(const bf16x8*)(As + aoff[i]);
            bfr[i] = *(const bf16x8*)(Bs + boff[i]);
        }
#pragma unroll
        for (int mi = 0; mi < 4; mi++)
#pragma unroll
            for (int nj = 0; nj < 4; nj++)
                acc[mi][nj] = __builtin_amdgcn_mfma_f32_16x16x32_bf16(
                    bfr[nj], af[mi], acc[mi][nj], 0, 0, 0);
        __syncthreads();
    }

#pragma unroll
    for (int mi = 0; mi < 4; mi++) {
        size_t rb = (size_t)(row0 + wm + mi * 16 + lrow) * INTER + n0 + wn + q * 4;
#pragma unroll
        for (int nj = 0; nj < 4; nj++) {
            f32x4 v = acc[mi][nj];
            bf16x4 o = {
                (bf16_t)(v.x * __builtin_amdgcn_rcpf(1.f + __expf(-v.x))),
                (bf16_t)(v.y * __builtin_amdgcn_rcpf(1.f + __expf(-v.y))),
                (bf16_t)(v.z * __builtin_amdgcn_rcpf(1.f + __expf(-v.z))),
                (bf16_t)(v.w * __builtin_amdgcn_rcpf(1.f + __expf(-v.w))) };
            *(bf16x4*)(Hbuf + rb + nj * 16) = o;
        }
    }
}

// ---------------- GEMM2: Obuf = Hbuf[rows] @ W2[e] ----------------------------
__global__ __launch_bounds__(256) void gemm2_kernel(
    const bf16_t* __restrict__ Hbuf, const bf16_t* __restrict__ w2t,
    const int* __restrict__ hdr, bf16_t* __restrict__ Obuf)
{
    __shared__ __align__(16) bf16_t As[BM * BK];
    __shared__ __align__(16) bf16_t Bs[BN * BK];

    int row0 = blockIdx.x * BM;
    int e = tile_expert(hdr, row0);
    if (e < 0) return;
    int n0 = blockIdx.y * BN;
    int tid = threadIdx.x;

    int ar0 = tid >> 2, as0 = tid & 3, ak0 = as0 ^ swz(ar0);
    int ar1 = ar0 + 64, ak1 = as0 ^ swz(ar1);
    const bf16_t* ag0 = Hbuf + (size_t)(row0 + ar0) * INTER + ak0 * 8;
    const bf16_t* ag1 = Hbuf + (size_t)(row0 + ar1) * INTER + ak1 * 8;
    bf16_t* al0 = As + tid * 8;
    bf16_t* al1 = As + (tid + 256) * 8;

    const bf16_t* wb = w2t + (size_t)e * HIDDEN * INTER;
    const bf16_t* bg0 = wb + (size_t)(n0 + ar0) * INTER + ak0 * 8;
    const bf16_t* bg1 = wb + (size_t)(n0 + ar1) * INTER + ak1 * 8;
    bf16_t* bl0 = Bs + tid * 8;
    bf16_t* bl1 = Bs + (tid + 256) * 8;

    int wave = tid >> 6, lane = tid & 63;
    int wm = (wave >> 1) * 64, wn = (wave & 1) * 64;
    int lrow = lane & 15, q = lane >> 4;

    int aoff[4], boff[4];
#pragma unroll
    for (int i = 0; i < 4; i++) {
        int r = wm + i * 16 + lrow;
        aoff[i] = r * BK + (q ^ swz(r)) * 8;
        int s = wn + i * 16 + lrow;
        boff[i] = s * BK + (q ^ swz(s)) * 8;
    }

    f32x4 acc[4][4] = {};

    for (int k0 = 0; k0 < INTER; k0 += BK) {
        async_cp16(ag0 + k0, al0);
        async_cp16(ag1 + k0, al1);
        async_cp16(bg0 + k0, bl0);
        async_cp16(bg1 + k0, bl1);
        __syncthreads();
        bf16x8 af[4], bfr[4];
#pragma unroll
        for (int i = 0; i < 4; i++) {
            af[i]  = *(const bf16x8*)(As + aoff[i]);
            bfr[i] = *(const bf16x8*)(Bs + boff[i]);
        }
#pragma unroll
        for (int mi = 0; mi < 4; mi++)
#pragma unroll
            for (int nj = 0; nj < 4; nj++)
                acc[mi][nj] = __builtin_amdgcn_mfma_f32_16x16x32_bf16(
                    bfr[nj], af[mi], acc[mi][nj], 0, 0, 0);
        __syncthreads();
    }

#pragma unroll
    for (int mi = 0; mi < 4; mi++) {
        size_t rb = (size_t)(row0 + wm + mi * 16 + lrow) * HIDDEN + n0 + wn + q * 4;
#pragma unroll
        for (int nj = 0; nj < 4; nj++) {
            f32x4 v = acc[mi][nj];
            bf16x4 o = { (bf16_t)v.x, (bf16_t)v.y, (bf16_t)v.z, (bf16_t)v.w };
            *(bf16x4*)(Obuf + rb + nj * 16) = o;
        }
    }
}

// ---------------- Combine: out[t] = w0*Obuf[r0] + w1*Obuf[r1] -----------------
__global__ __launch_bounds__(256) void combine_kernel(
    const bf16_t* __restrict__ Obuf, const int* __restrict__ row_of,
    const float* __restrict__ top_w, float* __restrict__ out)
{
    int t = blockIdx.x;
    int r0 = row_of[t * 2 + 0], r1 = row_of[t * 2 + 1];
    float w0 = top_w[t * 2 + 0], w1 = top_w[t * 2 + 1];
    int c = threadIdx.x * 4;
    bf16x4 a = *(const bf16x4*)(Obuf + (size_t)r0 * HIDDEN + c);
    bf16x4 b = *(const bf16x4*)(Obuf + (size_t)r1 * HIDDEN + c);
    float4 o;
    o.x = w0 * (float)a.x + w1 * (float)b.x;
    o.y = w0 * (float)a.y + w1 * (float)b.y;
    o.z = w0 * (float)a.z + w1 * (float)b.z;
    o.w = w0 * (float)a.w + w1 * (float)b.w;
    *(float4*)(out + (size_t)t * HIDDEN + c) = o;
}

// ---------------- Launch ------------------------------------------------------
extern "C" void kernel_launch(void* const* d_in, const int* in_sizes, int n_in,
                              void* d_out, int out_size, void* d_ws, size_t ws_size,
                              hipStream_t stream)
{
    const float* x  = (const float*)d_in[0];
    const float* wr = (const float*)d_in[1];
    const float* w1 = (const float*)d_in[2];
    const float* w2 = (const float*)d_in[3];
    float* out = (float*)d_out;

    int n = in_sizes[0] / HIDDEN;                                  // 8192
    int nblk = n / 4;                                              // 2048
    int rowcap = ((2 * n + NEXP * (BM - 1)) + BM - 1) / BM * BM;   // 17408

    char* ws = (char*)d_ws;
    int* hdr = (int*)ws;
    size_t off = 512;
    int* row_tok = (int*)(ws + off); off += (size_t)rowcap * 4;
    int* row_of  = (int*)(ws + off); off += (size_t)n * 2 * 4;
    int* top_e   = (int*)(ws + off); off += (size_t)n * 2 * 4;
    float* top_w = (float*)(ws + off); off += (size_t)n * 2 * 4;
    float* psums = (float*)(ws + off); off += (size_t)nblk * NEXP * 4;
    off = (off + 255) & ~(size_t)255;
    size_t xbf_off = off;
    bf16_t* xbf = (bf16_t*)(ws + off);  off += (size_t)n * HIDDEN * 2;
    bf16_t* w1t = (bf16_t*)(ws + off);  off += (size_t)NEXP * HIDDEN * INTER * 2;
    bf16_t* w2t = (bf16_t*)(ws + off);  off += (size_t)NEXP * HIDDEN * INTER * 2;
    bf16_t* Hbuf = (bf16_t*)(ws + off); off += (size_t)rowcap * INTER * 2;
    bf16_t* Obuf = (bf16_t*)(ws + xbf_off);   // aliases xbf+w1t (dead after gemm1)

    prep_kernel<<<NTBLK + nblk, 256, 0, stream>>>(
        x, wr, w1, w2, w1t, w2t, top_e, top_w, psums, xbf, hdr);
    hist_kernel<<<n / 256, 256, 0, stream>>>(top_e, hdr);
    setup_kernel<<<1, 256, 0, stream>>>(hdr, psums, nblk, row_tok,
                                        out + (out_size - 1), n);
    scatter_kernel<<<n / 256, 256, 0, stream>>>(top_e, hdr, row_tok, row_of);

    dim3 g1(rowcap / BM, INTER / BN);
    gemm1_kernel<<<g1, 256, 0, stream>>>(xbf, w1t, hdr, row_tok, Hbuf);
    dim3 g2(rowcap / BM, HIDDEN / BN);
    gemm2_kernel<<<g2, 256, 0, stream>>>(Hbuf, w2t, hdr, Obuf);
    combine_kernel<<<n, 256, 0, stream>>>(Obuf, row_of, top_w, out);
}